// Round 1
// baseline (1335.641 us; speedup 1.0000x reference)
//
#include <hip/hip_runtime.h>
#include <hip/hip_bf16.h>

#define BSZ 16
#define TT 4096
#define UU 128
#define OO 128
#define SS 256
#define HH 512
#define BT (BSZ*TT)      // 65536 rows
#define CL 64            // scan chunk length
#define NCH (TT/CL)      // 64 chunks per sequence

// ---------------- generic small transpose: out[c][r] = in[r][c] ----------------
__global__ void transpose_k(const float* __restrict__ in, float* __restrict__ out,
                            int R, int C){
  int i = blockIdx.x * 256 + threadIdx.x;
  if (i < R * C){
    int r = i / C, c = i - r * C;
    out[(size_t)c * R + r] = in[i];
  }
}

// ---------------- bu = input @ B^T  (Bt is [U][S]) ----------------
__global__ __launch_bounds__(256) void bu_gemm(const float* __restrict__ inp,
                                               const float* __restrict__ Bt,
                                               float* __restrict__ bu){
  __shared__ float sIn[16][UU];
  const int tid = threadIdx.x;
  const size_t bt0 = (size_t)blockIdx.x * 16;
  for (int j = tid; j < 16*(UU/4); j += 256){
    int r = j >> 5, c = j & 31;
    ((float4*)sIn[r])[c] = ((const float4*)(inp + (bt0 + r)*UU))[c];
  }
  __syncthreads();
  const int rg = tid >> 6, cg = tid & 63;
  const int r0 = rg * 4;
  float acc[4][4] = {};
  #pragma unroll 4
  for (int k = 0; k < UU; k++){
    float w0 = Bt[k*SS + cg];
    float w1 = Bt[k*SS + cg + 64];
    float w2 = Bt[k*SS + cg + 128];
    float w3 = Bt[k*SS + cg + 192];
    #pragma unroll
    for (int i = 0; i < 4; i++){
      float a = sIn[r0+i][k];
      acc[i][0] = fmaf(a, w0, acc[i][0]);
      acc[i][1] = fmaf(a, w1, acc[i][1]);
      acc[i][2] = fmaf(a, w2, acc[i][2]);
      acc[i][3] = fmaf(a, w3, acc[i][3]);
    }
  }
  #pragma unroll
  for (int i = 0; i < 4; i++)
    #pragma unroll
    for (int j = 0; j < 4; j++)
      bu[(bt0 + r0 + i)*SS + cg + 64*j] = acc[i][j];
}

// ---------------- scan phase 1: per-chunk end state (h0 = 0) ----------------
__global__ __launch_bounds__(256) void scan_ends(const float* __restrict__ bu,
                                                 const float* __restrict__ lre,
                                                 const float* __restrict__ lim,
                                                 float2* __restrict__ ends){
  const int s = threadIdx.x;
  const int b = blockIdx.x >> 6;     // NCH = 64
  const int c = blockIdx.x & 63;
  const float lr = lre[s], li = lim[s];
  float hr = 0.f, hi = 0.f;
  const float* p = bu + ((size_t)b*TT + (size_t)c*CL)*SS + s;
  #pragma unroll 8
  for (int t = 0; t < CL; t++){
    float x  = p[(size_t)t * SS];
    float nr = fmaf(lr, hr, fmaf(-li, hi, x));
    float ni = fmaf(lr, hi, li * hr);
    hr = nr; hi = ni;
  }
  ends[((size_t)b*NCH + c)*SS + s] = make_float2(hr, hi);
}

// ---------------- scan phase 2: carry scan across chunks ----------------
__global__ __launch_bounds__(256) void scan_carries(const float2* __restrict__ ends,
                                                    const float* __restrict__ lre,
                                                    const float* __restrict__ lim,
                                                    float2* __restrict__ carryin){
  const int idx = blockIdx.x * 256 + threadIdx.x;   // over B*S = 4096
  const int b = idx >> 8;
  const int s = idx & 255;
  float pr = lre[s], pi = lim[s];
  #pragma unroll
  for (int q = 0; q < 6; q++){      // lam^CL, CL = 64 = 2^6, by squaring
    float nr = pr*pr - pi*pi;
    float ni = 2.f * pr * pi;
    pr = nr; pi = ni;
  }
  float hr = 0.f, hi = 0.f;
  for (int c = 0; c < NCH; c++){
    size_t o = ((size_t)b*NCH + c)*SS + s;
    carryin[o] = make_float2(hr, hi);
    float2 e = ends[o];
    float nr = fmaf(pr, hr, fmaf(-pi, hi, e.x));
    float ni = fmaf(pr, hi, fmaf(pi, hr, e.y));
    hr = nr; hi = ni;
  }
}

// ---------------- scan phase 3: replay chunk with carry, write Re(h) in place ----------------
__global__ __launch_bounds__(256) void scan_apply(float* __restrict__ bu,
                                                  const float* __restrict__ lre,
                                                  const float* __restrict__ lim,
                                                  const float2* __restrict__ carryin){
  const int s = threadIdx.x;
  const int b = blockIdx.x >> 6;
  const int c = blockIdx.x & 63;
  const float lr = lre[s], li = lim[s];
  float2 h0 = carryin[((size_t)b*NCH + c)*SS + s];
  float hr = h0.x, hi = h0.y;
  float* p = bu + ((size_t)b*TT + (size_t)c*CL)*SS + s;
  #pragma unroll 4
  for (int t = 0; t < CL; t++){
    float x  = p[(size_t)t * SS];
    float nr = fmaf(lr, hr, fmaf(-li, hi, x));
    float ni = fmaf(lr, hi, li * hr);
    hr = nr; hi = ni;
    p[(size_t)t * SS] = hr;          // overwrite bu with Re(h)
  }
}

// ---------------- fused readout + MLP + residual ----------------
// y = Reh @ C^T + in @ D^T ; z1 = silu(y@W1^T) ; z2 = relu(z1@W2^T)
// out = z2 @ W3^T + in @ Wlin^T
// Weight matrices passed pre-transposed as [K][N] for coalesced lane loads.
__global__ __launch_bounds__(256) void fused_mlp(
    const float* __restrict__ Reh, const float* __restrict__ inp,
    const float* __restrict__ Ct,  const float* __restrict__ Dt,
    const float* __restrict__ W1t, const float* __restrict__ W2t,
    const float* __restrict__ W3t, const float* __restrict__ Wlt,
    float* __restrict__ out)
{
  __shared__ float sIn[16][UU];    // 8 KB
  __shared__ float sY [16][OO];    // 8 KB
  __shared__ float sAct[16][HH];   // 32 KB: holds Reh tile (16x256), then z1 (16x512)
  __shared__ float sZ2[16][HH];    // 32 KB
  const int tid = threadIdx.x;
  const size_t bt0 = (size_t)blockIdx.x * 16;

  for (int j = tid; j < 16*(UU/4); j += 256){
    int r = j >> 5, c = j & 31;
    ((float4*)sIn[r])[c] = ((const float4*)(inp + (bt0 + r)*UU))[c];
  }
  for (int j = tid; j < 16*(SS/4); j += 256){
    int r = j >> 6, c = j & 63;
    ((float4*)sAct[r])[c] = ((const float4*)(Reh + (bt0 + r)*SS))[c];
  }
  __syncthreads();

  const int rg = tid >> 6, cg = tid & 63;   // rg wave-uniform -> LDS broadcasts
  const int r0 = rg * 4;

  // ---- S1: y ----
  {
    float acc[4][2] = {};
    #pragma unroll 2
    for (int k = 0; k < SS; k++){
      float w0 = Ct[k*OO + cg], w1 = Ct[k*OO + cg + 64];
      #pragma unroll
      for (int i = 0; i < 4; i++){
        float a = sAct[r0+i][k];
        acc[i][0] = fmaf(a, w0, acc[i][0]);
        acc[i][1] = fmaf(a, w1, acc[i][1]);
      }
    }
    #pragma unroll 2
    for (int k = 0; k < UU; k++){
      float w0 = Dt[k*OO + cg], w1 = Dt[k*OO + cg + 64];
      #pragma unroll
      for (int i = 0; i < 4; i++){
        float a = sIn[r0+i][k];
        acc[i][0] = fmaf(a, w0, acc[i][0]);
        acc[i][1] = fmaf(a, w1, acc[i][1]);
      }
    }
    #pragma unroll
    for (int i = 0; i < 4; i++){
      sY[r0+i][cg]      = acc[i][0];
      sY[r0+i][cg + 64] = acc[i][1];
    }
    __syncthreads();   // sY visible; all sAct (Reh) reads done
  }

  // ---- S2: z1 = silu(y @ W1^T) -> sAct ----
  {
    float acc[4][8] = {};
    #pragma unroll 2
    for (int k = 0; k < OO; k++){
      float a[4];
      #pragma unroll
      for (int i = 0; i < 4; i++) a[i] = sY[r0+i][k];
      #pragma unroll
      for (int j = 0; j < 8; j++){
        float w = W1t[k*HH + cg + 64*j];
        #pragma unroll
        for (int i = 0; i < 4; i++) acc[i][j] = fmaf(a[i], w, acc[i][j]);
      }
    }
    #pragma unroll
    for (int i = 0; i < 4; i++)
      #pragma unroll
      for (int j = 0; j < 8; j++){
        float v = acc[i][j];
        v = v / (1.f + __expf(-v));          // silu
        sAct[r0+i][cg + 64*j] = v;
      }
    __syncthreads();
  }

  // ---- S3: z2 = relu(z1 @ W2^T) -> sZ2 ----
  {
    float acc[4][8] = {};
    #pragma unroll 2
    for (int k = 0; k < HH; k++){
      float a[4];
      #pragma unroll
      for (int i = 0; i < 4; i++) a[i] = sAct[r0+i][k];
      #pragma unroll
      for (int j = 0; j < 8; j++){
        float w = W2t[k*HH + cg + 64*j];
        #pragma unroll
        for (int i = 0; i < 4; i++) acc[i][j] = fmaf(a[i], w, acc[i][j]);
      }
    }
    #pragma unroll
    for (int i = 0; i < 4; i++)
      #pragma unroll
      for (int j = 0; j < 8; j++)
        sZ2[r0+i][cg + 64*j] = fmaxf(acc[i][j], 0.f);
    __syncthreads();
  }

  // ---- S4: out = z2 @ W3^T + in @ Wlin^T ----
  {
    float acc[4][2] = {};
    #pragma unroll 2
    for (int k = 0; k < HH; k++){
      float w0 = W3t[k*OO + cg], w1 = W3t[k*OO + cg + 64];
      #pragma unroll
      for (int i = 0; i < 4; i++){
        float a = sZ2[r0+i][k];
        acc[i][0] = fmaf(a, w0, acc[i][0]);
        acc[i][1] = fmaf(a, w1, acc[i][1]);
      }
    }
    #pragma unroll 2
    for (int k = 0; k < UU; k++){
      float w0 = Wlt[k*OO + cg], w1 = Wlt[k*OO + cg + 64];
      #pragma unroll
      for (int i = 0; i < 4; i++){
        float a = sIn[r0+i][k];
        acc[i][0] = fmaf(a, w0, acc[i][0]);
        acc[i][1] = fmaf(a, w1, acc[i][1]);
      }
    }
    #pragma unroll
    for (int i = 0; i < 4; i++){
      out[(bt0 + r0 + i)*OO + cg]      = acc[i][0];
      out[(bt0 + r0 + i)*OO + cg + 64] = acc[i][1];
    }
  }
}

extern "C" void kernel_launch(void* const* d_in, const int* in_sizes, int n_in,
                              void* d_out, int out_size, void* d_ws, size_t ws_size,
                              hipStream_t stream){
  const float* inp = (const float*)d_in[0];
  const float* lre = (const float*)d_in[1];
  const float* lim = (const float*)d_in[2];
  const float* Bm  = (const float*)d_in[3];
  const float* Cm  = (const float*)d_in[4];
  const float* Dm  = (const float*)d_in[5];
  const float* W1  = (const float*)d_in[6];
  const float* W2  = (const float*)d_in[7];
  const float* W3  = (const float*)d_in[8];
  const float* Wl  = (const float*)d_in[9];
  float* out = (float*)d_out;

  char* ws = (char*)d_ws;
  size_t off = 0;
  float*  bu      = (float*)(ws + off);  off += (size_t)BT * SS * 4;          // 64 MB (bu -> Re(h) in place)
  float2* ends    = (float2*)(ws + off); off += (size_t)BSZ * NCH * SS * 8;   // 2 MB
  float2* carryin = (float2*)(ws + off); off += (size_t)BSZ * NCH * SS * 8;   // 2 MB
  float*  Bt  = (float*)(ws + off); off += (size_t)UU * SS * 4;
  float*  Ct  = (float*)(ws + off); off += (size_t)SS * OO * 4;
  float*  Dt  = (float*)(ws + off); off += (size_t)UU * OO * 4;
  float*  W1t = (float*)(ws + off); off += (size_t)OO * HH * 4;
  float*  W2t = (float*)(ws + off); off += (size_t)HH * HH * 4;
  float*  W3t = (float*)(ws + off); off += (size_t)HH * OO * 4;
  float*  Wlt = (float*)(ws + off); off += (size_t)UU * OO * 4;

  // weight transposes (tiny)
  transpose_k<<<(SS*UU + 255)/256, 256, 0, stream>>>(Bm, Bt, SS, UU);
  transpose_k<<<(OO*SS + 255)/256, 256, 0, stream>>>(Cm, Ct, OO, SS);
  transpose_k<<<(OO*UU + 255)/256, 256, 0, stream>>>(Dm, Dt, OO, UU);
  transpose_k<<<(HH*OO + 255)/256, 256, 0, stream>>>(W1, W1t, HH, OO);
  transpose_k<<<(HH*HH + 255)/256, 256, 0, stream>>>(W2, W2t, HH, HH);
  transpose_k<<<(OO*HH + 255)/256, 256, 0, stream>>>(W3, W3t, OO, HH);
  transpose_k<<<(OO*UU + 255)/256, 256, 0, stream>>>(Wl, Wlt, OO, UU);

  bu_gemm<<<BT/16, 256, 0, stream>>>(inp, Bt, bu);
  scan_ends<<<BSZ*NCH, 256, 0, stream>>>(bu, lre, lim, ends);
  scan_carries<<<(BSZ*SS)/256, 256, 0, stream>>>(ends, lre, lim, carryin);
  scan_apply<<<BSZ*NCH, 256, 0, stream>>>(bu, lre, lim, carryin);
  fused_mlp<<<BT/16, 256, 0, stream>>>(bu, inp, Ct, Dt, W1t, W2t, W3t, Wlt, out);
}

// Round 2
// 394.681 us; speedup vs baseline: 3.3841x; 3.3841x over previous
//
#include <hip/hip_runtime.h>
#include <hip/hip_bf16.h>

#define BSZ 16
#define TT 4096
#define UU 128
#define OO 128
#define SS 256
#define HH 512
#define BT (BSZ*TT)      // 65536 rows
#define CL 64            // scan chunk length
#define NCH (TT/CL)      // 64 chunks per sequence

using bf16x8 = __attribute__((ext_vector_type(8))) short;
using f32x4  = __attribute__((ext_vector_type(4))) float;

__device__ __forceinline__ unsigned short f2bf(float x){
  union { float f; unsigned int u; } v; v.f = x;
  unsigned int r = v.u + 0x7fffu + ((v.u >> 16) & 1u);
  return (unsigned short)(r >> 16);
}
__device__ __forceinline__ float bf2f(unsigned short h){
  union { float f; unsigned int u; } v; v.u = ((unsigned int)h) << 16;
  return v.f;
}

// async global->LDS, 16B per lane
#define GLD16(g, s) __builtin_amdgcn_global_load_lds( \
    (const __attribute__((address_space(1))) unsigned int*)(g), \
    (__attribute__((address_space(3))) unsigned int*)(s), 16, 0, 0)

// ---------------- split fp32 -> (hi, lo) bf16 planes ----------------
__global__ __launch_bounds__(256) void split_k(const float* __restrict__ x,
                                               unsigned short* __restrict__ H,
                                               unsigned short* __restrict__ L, int n4){
  int i = blockIdx.x * 256 + threadIdx.x;
  if (i >= n4) return;
  float4 v = ((const float4*)x)[i];
  unsigned short h0 = f2bf(v.x), h1 = f2bf(v.y), h2 = f2bf(v.z), h3 = f2bf(v.w);
  ushort4 hh = make_ushort4(h0, h1, h2, h3);
  ushort4 ll = make_ushort4(f2bf(v.x - bf2f(h0)), f2bf(v.y - bf2f(h1)),
                            f2bf(v.z - bf2f(h2)), f2bf(v.w - bf2f(h3)));
  ((ushort4*)H)[i] = hh;
  ((ushort4*)L)[i] = ll;
}

// ---------------- generic split-precision MFMA GEMM ----------------
// C[M][Nout] = A1*B1^T (+ A2*B2^T), A as (hi,lo) bf16 planes [rows][K],
// B as (hi,lo) planes [N][K] (weights in native row-major layout).
// 3-term split: ah*bh + al*bh + ah*bl, fp32 accumulate (~fp32 accuracy).
// EPI: 0 = fp32 store, 1 = split store, 2 = silu+split, 3 = relu+split.
__global__ __launch_bounds__(256, 2) void gemm_split(
    const unsigned short* __restrict__ AH1, const unsigned short* __restrict__ AL1,
    const unsigned short* __restrict__ BH1, const unsigned short* __restrict__ BL1, int K1,
    const unsigned short* __restrict__ AH2, const unsigned short* __restrict__ AL2,
    const unsigned short* __restrict__ BH2, const unsigned short* __restrict__ BL2, int K2,
    unsigned short* __restrict__ outH, unsigned short* __restrict__ outL,
    float* __restrict__ outF, int Nout, int EPI)
{
  __shared__ __align__(16) unsigned short Ah[128*64];
  __shared__ __align__(16) unsigned short Al[128*64];
  __shared__ __align__(16) unsigned short Bh[128*64];
  __shared__ __align__(16) unsigned short Bl[128*64];
  const int tid = threadIdx.x;
  const int mb = blockIdx.x, nb = blockIdx.y;
  const int l = tid & 63, w = tid >> 6;
  const int wr = w >> 1, wc = w & 1;
  const int fr = l & 15, fq = l >> 4;

  f32x4 acc[4][4];
  #pragma unroll
  for (int m = 0; m < 4; m++)
    #pragma unroll
    for (int n = 0; n < 4; n++) acc[m][n] = f32x4{0.f, 0.f, 0.f, 0.f};

  const int nkt = (K1 + K2) >> 6;
  for (int kt = 0; kt < nkt; kt++){
    const int k0 = kt << 6;
    const unsigned short *aH, *aL, *bH, *bL; int st, kk;
    if (k0 < K1){ aH = AH1; aL = AL1; bH = BH1; bL = BL1; st = K1; kk = k0; }
    else        { aH = AH2; aL = AL2; bH = BH2; bL = BL2; st = K2; kk = k0 - K1; }
    __syncthreads();
    #pragma unroll
    for (int it = 0; it < 4; it++){
      int seg = tid + it * 256;            // 1024 segments of 16B per tile
      int r = seg >> 3, c8 = seg & 7;
      size_t go = (size_t)(mb*128 + r) * st + kk + c8*8;
      int lo = r*64 + c8*8;
      GLD16(aH + go, Ah + lo);
      GLD16(aL + go, Al + lo);
      size_t gb = (size_t)(nb*128 + r) * st + kk + c8*8;
      GLD16(bH + gb, Bh + lo);
      GLD16(bL + gb, Bl + lo);
    }
    __syncthreads();
    #pragma unroll
    for (int ks = 0; ks < 2; ks++){
      const int ko = ks*32 + fq*8;
      bf16x8 a_h[4], a_l[4], b_h[4], b_l[4];
      #pragma unroll
      for (int m = 0; m < 4; m++){
        int ra = (wr*64 + m*16 + fr)*64 + ko;
        a_h[m] = *(const bf16x8*)&Ah[ra];
        a_l[m] = *(const bf16x8*)&Al[ra];
        int rb = (wc*64 + m*16 + fr)*64 + ko;
        b_h[m] = *(const bf16x8*)&Bh[rb];
        b_l[m] = *(const bf16x8*)&Bl[rb];
      }
      #pragma unroll
      for (int m = 0; m < 4; m++)
        #pragma unroll
        for (int n = 0; n < 4; n++)
          acc[m][n] = __builtin_amdgcn_mfma_f32_16x16x32_bf16(a_h[m], b_h[n], acc[m][n], 0, 0, 0);
      #pragma unroll
      for (int m = 0; m < 4; m++)
        #pragma unroll
        for (int n = 0; n < 4; n++)
          acc[m][n] = __builtin_amdgcn_mfma_f32_16x16x32_bf16(a_l[m], b_h[n], acc[m][n], 0, 0, 0);
      #pragma unroll
      for (int m = 0; m < 4; m++)
        #pragma unroll
        for (int n = 0; n < 4; n++)
          acc[m][n] = __builtin_amdgcn_mfma_f32_16x16x32_bf16(a_h[m], b_l[n], acc[m][n], 0, 0, 0);
    }
  }

  #pragma unroll
  for (int m = 0; m < 4; m++){
    int rowb = mb*128 + wr*64 + m*16 + fq*4;
    #pragma unroll
    for (int n = 0; n < 4; n++){
      int col = nb*128 + wc*64 + n*16 + fr;
      #pragma unroll
      for (int j = 0; j < 4; j++){
        float x = acc[m][n][j];
        size_t o = (size_t)(rowb + j) * Nout + col;
        if (EPI == 0){
          outF[o] = x;
        } else {
          if (EPI == 2)      x = x / (1.f + __expf(-x));   // silu
          else if (EPI == 3) x = fmaxf(x, 0.f);            // relu
          unsigned short h = f2bf(x);
          outH[o] = h;
          outL[o] = f2bf(x - bf2f(h));
        }
      }
    }
  }
}

// ---------------- scan phase 1: per-chunk end state (h0 = 0) ----------------
__global__ __launch_bounds__(256) void scan_ends(const float* __restrict__ bu,
                                                 const float* __restrict__ lre,
                                                 const float* __restrict__ lim,
                                                 float2* __restrict__ ends){
  const int s = threadIdx.x;
  const int b = blockIdx.x >> 6;
  const int c = blockIdx.x & 63;
  const float lr = lre[s], li = lim[s];
  float hr = 0.f, hi = 0.f;
  const float* p = bu + ((size_t)b*TT + (size_t)c*CL)*SS + s;
  #pragma unroll 8
  for (int t = 0; t < CL; t++){
    float x  = p[(size_t)t * SS];
    float nr = fmaf(lr, hr, fmaf(-li, hi, x));
    float ni = fmaf(lr, hi, li * hr);
    hr = nr; hi = ni;
  }
  ends[((size_t)b*NCH + c)*SS + s] = make_float2(hr, hi);
}

// ---------------- scan phase 2: carry scan across chunks ----------------
__global__ __launch_bounds__(256) void scan_carries(const float2* __restrict__ ends,
                                                    const float* __restrict__ lre,
                                                    const float* __restrict__ lim,
                                                    float2* __restrict__ carryin){
  const int idx = blockIdx.x * 256 + threadIdx.x;   // over B*S = 4096
  const int b = idx >> 8;
  const int s = idx & 255;
  float pr = lre[s], pi = lim[s];
  #pragma unroll
  for (int q = 0; q < 6; q++){      // lam^64 by squaring
    float nr = pr*pr - pi*pi;
    float ni = 2.f * pr * pi;
    pr = nr; pi = ni;
  }
  float hr = 0.f, hi = 0.f;
  for (int c = 0; c < NCH; c++){
    size_t o = ((size_t)b*NCH + c)*SS + s;
    carryin[o] = make_float2(hr, hi);
    float2 e = ends[o];
    float nr = fmaf(pr, hr, fmaf(-pi, hi, e.x));
    float ni = fmaf(pr, hi, fmaf(pi, hr, e.y));
    hr = nr; hi = ni;
  }
}

// ---------------- scan phase 3: replay chunk, write Re(h) split planes ----------------
__global__ __launch_bounds__(256) void scan_apply(const float* __restrict__ bu,
                                                  const float* __restrict__ lre,
                                                  const float* __restrict__ lim,
                                                  const float2* __restrict__ carryin,
                                                  unsigned short* __restrict__ RehH,
                                                  unsigned short* __restrict__ RehL){
  const int s = threadIdx.x;
  const int b = blockIdx.x >> 6;
  const int c = blockIdx.x & 63;
  const float lr = lre[s], li = lim[s];
  float2 h0 = carryin[((size_t)b*NCH + c)*SS + s];
  float hr = h0.x, hi = h0.y;
  const size_t base = ((size_t)b*TT + (size_t)c*CL)*SS + s;
  #pragma unroll 4
  for (int t = 0; t < CL; t++){
    float x  = bu[base + (size_t)t * SS];
    float nr = fmaf(lr, hr, fmaf(-li, hi, x));
    float ni = fmaf(lr, hi, li * hr);
    hr = nr; hi = ni;
    unsigned short h = f2bf(hr);
    RehH[base + (size_t)t * SS] = h;
    RehL[base + (size_t)t * SS] = f2bf(hr - bf2f(h));
  }
}

extern "C" void kernel_launch(void* const* d_in, const int* in_sizes, int n_in,
                              void* d_out, int out_size, void* d_ws, size_t ws_size,
                              hipStream_t stream){
  const float* inp = (const float*)d_in[0];
  const float* lre = (const float*)d_in[1];
  const float* lim = (const float*)d_in[2];
  const float* Bm  = (const float*)d_in[3];
  const float* Cm  = (const float*)d_in[4];
  const float* Dm  = (const float*)d_in[5];
  const float* W1  = (const float*)d_in[6];
  const float* W2  = (const float*)d_in[7];
  const float* W3  = (const float*)d_in[8];
  const float* Wl  = (const float*)d_in[9];
  float* out = (float*)d_out;

  char* ws = (char*)d_ws;
  size_t off = 0;
  auto alloc = [&](size_t bytes)->char*{
    char* p = ws + off; off += (bytes + 255) & ~(size_t)255; return p;
  };
  unsigned short* inH = (unsigned short*)alloc((size_t)BT*UU*2);
  unsigned short* inL = (unsigned short*)alloc((size_t)BT*UU*2);
  unsigned short* BwH = (unsigned short*)alloc((size_t)SS*UU*2);
  unsigned short* BwL = (unsigned short*)alloc((size_t)SS*UU*2);
  unsigned short* CH_ = (unsigned short*)alloc((size_t)OO*SS*2);
  unsigned short* CL_ = (unsigned short*)alloc((size_t)OO*SS*2);
  unsigned short* DH_ = (unsigned short*)alloc((size_t)OO*UU*2);
  unsigned short* DL_ = (unsigned short*)alloc((size_t)OO*UU*2);
  unsigned short* W1H = (unsigned short*)alloc((size_t)HH*OO*2);
  unsigned short* W1L = (unsigned short*)alloc((size_t)HH*OO*2);
  unsigned short* W2H = (unsigned short*)alloc((size_t)HH*HH*2);
  unsigned short* W2L = (unsigned short*)alloc((size_t)HH*HH*2);
  unsigned short* W3H = (unsigned short*)alloc((size_t)OO*HH*2);
  unsigned short* W3L = (unsigned short*)alloc((size_t)OO*HH*2);
  unsigned short* WlH = (unsigned short*)alloc((size_t)OO*UU*2);
  unsigned short* WlL = (unsigned short*)alloc((size_t)OO*UU*2);
  float2* ends    = (float2*)alloc((size_t)BSZ*NCH*SS*8);
  float2* carryin = (float2*)alloc((size_t)BSZ*NCH*SS*8);
  // region R1: bu (64 MB) -> reused for z1 planes (32+32 MB) in MLP phase
  char* R1 = alloc((size_t)BT*SS*4);
  float* bu = (float*)R1;
  unsigned short* z1H = (unsigned short*)R1;
  unsigned short* z1L = (unsigned short*)(R1 + (size_t)(BT/2)*HH*2);
  // region R2: Reh planes (32+32 MB) -> reused for z2 planes in MLP phase
  char* R2 = alloc((size_t)BT*SS*4);
  unsigned short* RehH = (unsigned short*)R2;
  unsigned short* RehL = (unsigned short*)(R2 + (size_t)BT*SS*2);
  unsigned short* z2H  = (unsigned short*)R2;
  unsigned short* z2L  = (unsigned short*)(R2 + (size_t)(BT/2)*HH*2);
  unsigned short* yH = (unsigned short*)alloc((size_t)BT*OO*2);
  unsigned short* yL = (unsigned short*)alloc((size_t)BT*OO*2);
  if (off > ws_size) return;   // fail loudly (poisoned output) rather than corrupt

  // ---- split input + weights into bf16 hi/lo planes ----
  split_k<<<(BT*UU/4 + 255)/256, 256, 0, stream>>>(inp, inH, inL, BT*UU/4);
  split_k<<<(SS*UU/4 + 255)/256, 256, 0, stream>>>(Bm, BwH, BwL, SS*UU/4);
  split_k<<<(OO*SS/4 + 255)/256, 256, 0, stream>>>(Cm, CH_, CL_, OO*SS/4);
  split_k<<<(OO*UU/4 + 255)/256, 256, 0, stream>>>(Dm, DH_, DL_, OO*UU/4);
  split_k<<<(HH*OO/4 + 255)/256, 256, 0, stream>>>(W1, W1H, W1L, HH*OO/4);
  split_k<<<(HH*HH/4 + 255)/256, 256, 0, stream>>>(W2, W2H, W2L, HH*HH/4);
  split_k<<<(OO*HH/4 + 255)/256, 256, 0, stream>>>(W3, W3H, W3L, OO*HH/4);
  split_k<<<(OO*UU/4 + 255)/256, 256, 0, stream>>>(Wl, WlH, WlL, OO*UU/4);

  // ---- bu = input @ B^T (fp32 out for the scan) ----
  gemm_split<<<dim3(BT/128, SS/128), 256, 0, stream>>>(
      inH, inL, BwH, BwL, UU,  inH, inL, BwH, BwL, 0,
      nullptr, nullptr, bu, SS, 0);

  // ---- diagonal complex scan ----
  scan_ends<<<BSZ*NCH, 256, 0, stream>>>(bu, lre, lim, ends);
  scan_carries<<<(BSZ*SS)/256, 256, 0, stream>>>(ends, lre, lim, carryin);
  scan_apply<<<BSZ*NCH, 256, 0, stream>>>(bu, lre, lim, carryin, RehH, RehL);

  // ---- y = Re(h)@C^T + in@D^T ----
  gemm_split<<<dim3(BT/128, OO/128), 256, 0, stream>>>(
      RehH, RehL, CH_, CL_, SS,  inH, inL, DH_, DL_, UU,
      yH, yL, nullptr, OO, 1);

  // ---- MLP per batch-half (bounds workspace footprint) ----
  for (int c = 0; c < 2; c++){
    const size_t ro = (size_t)c * (BT/2);
    gemm_split<<<dim3(BT/2/128, HH/128), 256, 0, stream>>>(
        yH + ro*OO, yL + ro*OO, W1H, W1L, OO,
        yH, yL, W1H, W1L, 0,
        z1H, z1L, nullptr, HH, 2);                       // silu
    gemm_split<<<dim3(BT/2/128, HH/128), 256, 0, stream>>>(
        z1H, z1L, W2H, W2L, HH,
        z1H, z1L, W2H, W2L, 0,
        z2H, z2L, nullptr, HH, 3);                       // relu
    gemm_split<<<dim3(BT/2/128, OO/128), 256, 0, stream>>>(
        z2H, z2L, W3H, W3L, HH,
        inH + ro*UU, inL + ro*UU, WlH, WlL, UU,
        nullptr, nullptr, out + ro*OO, OO, 0);           // fp32 out + residual
  }
}